// Round 5
// baseline (195.557 us; speedup 1.0000x reference)
//
#include <hip/hip_runtime.h>
#include <hip/hip_bf16.h>

typedef unsigned int u32;
typedef __attribute__((ext_vector_type(8))) short bf16x8;    // 8 bf16 = 4 VGPRs (MFMA A/B frag)
typedef __attribute__((ext_vector_type(16))) float f32x16;   // MFMA C/D frag
typedef __attribute__((ext_vector_type(4))) u32 u32x4;

// ---------------------------------------------------------------------------
// PillarFeatureNet fused (round 5: R4 math + full occupancy)
//
//   features (N,32,4) f32 | num_points (N,) i32 | coors (N,4) i32 [b,z,y,x]
//   W (63,9) f32 | gamma/beta/running_mean/running_var (63,) f32
//   out (N,64) f32 = [relu(max-pool BN(linear(feats9)))[63] | num_points]
//
// R4 post-mortem: kernel was latency-bound at 2.5 waves/SIMD (1024-block
// grid). This round: 7500 blocks -> 8 blocks/CU resident (32 waves/CU),
// each wave handles 2 pillar-pairs. Math identical to the passing R4.
// ---------------------------------------------------------------------------

#define XOFF (0.08f)            // vx/2 + pc_range[0]
#define YOFF (0.08f - 39.68f)   // vy/2 + pc_range[1]

__device__ __forceinline__ u32 f2bf_bits(float f) {
    union { float f; u32 u; } v; v.f = f;
    u32 u = v.u;
    u += 0x7fffu + ((u >> 16) & 1u);   // RNE
    return u >> 16;
}
__device__ __forceinline__ short bf1(float f) { return (short)f2bf_bits(f); }

// packed bf16 convert: v_cvt_pk_bf16_f32 (1 instr)
__device__ __forceinline__ u32 pk2(float lo, float hi) {
    __hip_bfloat162 h = __float22bfloat162_rn(make_float2(lo, hi));
    union { __hip_bfloat162 h; u32 u; } v; v.h = h;
    return v.u;   // low 16 = lo, high 16 = hi
}

__device__ __forceinline__ float vmax16(const f32x16 v) {
    // balanced tree; compiler fuses to v_max3_f32 chains
    float a = fmaxf(fmaxf(v[0], v[1]), fmaxf(v[2], v[3]));
    float b = fmaxf(fmaxf(v[4], v[5]), fmaxf(v[6], v[7]));
    float c = fmaxf(fmaxf(v[8], v[9]), fmaxf(v[10], v[11]));
    float d = fmaxf(fmaxf(v[12], v[13]), fmaxf(v[14], v[15]));
    return fmaxf(fmaxf(a, b), fmaxf(c, d));
}

__global__ __launch_bounds__(256, 8)   // cap VGPR at 64 -> 8 waves/SIMD
void pfn_mfma(const float* __restrict__ features,
              const int* __restrict__ num_points,
              const int* __restrict__ coors,
              const float* __restrict__ W,
              const float* __restrict__ gamma,
              const float* __restrict__ beta,
              const float* __restrict__ rmean,
              const float* __restrict__ rvar,
              float* __restrict__ out,
              int n_total)
{
    const int lane = threadIdx.x & 63;
    const int wid  = threadIdx.x >> 6;
    const int half = lane >> 5;          // 0 = pillar A, 1 = pillar B
    const int m    = lane & 31;          // point index / channel within tile
    const int waves_total = gridDim.x * 4;
    const int gwave = blockIdx.x * 4 + wid;

    // ---- per-wave setup: fold BN into W, build B-frags -------------------
    const int c0 = m, c1 = 32 + m;       // tile0 ch 0..31, tile1 ch 32..63
    const float inv0   = gamma[c0] / sqrtf(rvar[c0] + 1e-3f);
    const float shift0 = beta[c0] - rmean[c0] * inv0;
    float inv1 = 0.0f, shift1 = 0.0f;
    if (c1 < 63) {
        inv1   = gamma[c1] / sqrtf(rvar[c1] + 1e-3f);
        shift1 = beta[c1] - rmean[c1] * inv1;
    }
    const float shift_me = half ? shift1 : shift0;

    // B[k][n]: n = lane&31 (channel within tile), k = half*8 + j
    bf16x8 b0, b1;
#pragma unroll
    for (int j = 0; j < 8; ++j) {
        const int k = half * 8 + j;
        b0[j] = bf1((k < 9) ? W[c0 * 9 + k] * inv0 : 0.0f);
        b1[j] = bf1((k < 9 && c1 < 63) ? W[c1 * 9 + k] * inv1 : 0.0f);
    }

    const float4* featv = reinterpret_cast<const float4*>(features);
    const int n_pairs = (n_total + 1) >> 1;

    for (int pair = gwave; pair < n_pairs; pair += waves_total) {
        const int nA  = pair * 2;
        const int n_h = nA + half;
        const bool act = (n_h < n_total);

        int npts = 1;
        float cxo = 0.f, cyo = 0.f;
        float4 q = make_float4(0.f, 0.f, 0.f, 0.f);
        if (act) {
            npts = num_points[n_h];
            const int2 cc = *reinterpret_cast<const int2*>(coors + n_h * 4 + 2); // [y, x]
            cxo = (float)cc.y * 0.16f + XOFF;
            cyo = (float)cc.x * 0.16f + YOFF;
            q = featv[n_h * 32 + m];     // 32-bit index: < 3.84M elements
        }

        // ---- centroid: sum ALL 32 points (incl. padding), / num_points ----
        float sx = q.x, sy = q.y, sz = q.z;
#pragma unroll
        for (int d = 1; d < 32; d <<= 1) {
            sx += __shfl_xor(sx, d, 32);
            sy += __shfl_xor(sy, d, 32);
            sz += __shfl_xor(sz, d, 32);
        }
        const float rnp = 1.0f / (float)npts;
        const float mx = sx * rnp, my = sy * rnp, mz = sz * rnp;

        // ---- 9-dim feature, packed bf16, masked ---------------------------
        u32 p0 = pk2(q.x, q.y);
        u32 p1 = pk2(q.z, q.w);
        u32 p2 = pk2(q.x - mx, q.y - my);
        u32 p3 = pk2(q.z - mz, q.x - cxo);
        u32 p4 = pk2(q.y - cyo, 0.0f);
        if (m >= npts) { p0 = 0; p1 = 0; p2 = 0; p3 = 0; p4 = 0; }

        // ---- cross-half exchange: 5 shuffles build both A-frags -----------
        const u32 x0 = __shfl_xor(p0, 32);
        const u32 x1 = __shfl_xor(p1, 32);
        const u32 x2 = __shfl_xor(p2, 32);
        const u32 x3 = __shfl_xor(p3, 32);
        const u32 x4 = __shfl_xor(p4, 32);

        // aA: lanes<32 = pillar A k0..7 (own p0..p3); lanes>=32 = k8..15 (x4,0,0,0)
        u32x4 adw, bdw;
        adw[0] = half ? x4 : p0;  adw[1] = half ? 0u : p1;
        adw[2] = half ? 0u : p2;  adw[3] = half ? 0u : p3;
        // aB: lanes<32 = pillar B k0..7 (x0..x3); lanes>=32 = k8..15 (p4,0,0,0)
        bdw[0] = half ? p4 : x0;  bdw[1] = half ? 0u : x1;
        bdw[2] = half ? 0u : x2;  bdw[3] = half ? 0u : x3;
        const bf16x8 aA = __builtin_bit_cast(bf16x8, adw);
        const bf16x8 aB = __builtin_bit_cast(bf16x8, bdw);

        f32x16 cA0 = {}, cA1 = {}, cB0 = {}, cB1 = {};
        cA0 = __builtin_amdgcn_mfma_f32_32x32x16_bf16(aA, b0, cA0, 0, 0, 0);
        cA1 = __builtin_amdgcn_mfma_f32_32x32x16_bf16(aA, b1, cA1, 0, 0, 0);
        cB0 = __builtin_amdgcn_mfma_f32_32x32x16_bf16(aB, b0, cB0, 0, 0, 0);
        cB1 = __builtin_amdgcn_mfma_f32_32x32x16_bf16(aB, b1, cB1, 0, 0, 0);

        // ---- epilogue: row-max (in-lane 16, then xor-32 half merge) -------
        float tA0 = vmax16(cA0), tA1 = vmax16(cA1);
        float tB0 = vmax16(cB0), tB1 = vmax16(cB1);
        tA0 = fmaxf(tA0, __shfl_xor(tA0, 32));
        tA1 = fmaxf(tA1, __shfl_xor(tA1, 32));
        tB0 = fmaxf(tB0, __shfl_xor(tB0, 32));
        tB1 = fmaxf(tB1, __shfl_xor(tB1, 32));

        float vA = fmaxf((half ? tA1 : tA0) + shift_me, 0.0f);
        float vB = fmaxf((half ? tB1 : tB0) + shift_me, 0.0f);

        // channel 63 = num_points; lane 63 needs BOTH pillars' counts
        const float npf = (float)npts;
        const float npA = __shfl(npf, 0);
        const float npB = __shfl(npf, 32);
        if (lane == 63) { vA = npA; vB = npB; }

        if (nA < n_total)     out[nA * 64 + lane] = vA;          // 32-bit offsets
        if (nA + 1 < n_total) out[(nA + 1) * 64 + lane] = vB;
    }
}

extern "C" void kernel_launch(void* const* d_in, const int* in_sizes, int n_in,
                              void* d_out, int out_size, void* d_ws, size_t ws_size,
                              hipStream_t stream) {
    const float* features   = (const float*)d_in[0];
    const int*   num_points = (const int*)d_in[1];
    const int*   coors      = (const int*)d_in[2];
    const float* W          = (const float*)d_in[3];
    const float* gamma      = (const float*)d_in[4];
    const float* beta       = (const float*)d_in[5];
    const float* rmean      = (const float*)d_in[6];
    const float* rvar       = (const float*)d_in[7];
    float* out              = (float*)d_out;

    const int n_total = in_sizes[1];   // N pillars

    // n_pairs = 60000. 7500 blocks x 4 waves = 30000 waves -> 2 pairs/wave.
    // ~117 blocks/CU queued -> resident cap 8 blocks/CU = 32 waves/CU.
    const int n_pairs = (n_total + 1) / 2;
    const int waves   = (n_pairs + 1) / 2;            // 2 pairs per wave
    const int blocks  = (waves + 3) / 4;
    pfn_mfma<<<blocks, 256, 0, stream>>>(features, num_points, coors, W,
                                         gamma, beta, rmean, rvar, out, n_total);
}

// Round 6
// 135.895 us; speedup vs baseline: 1.4390x; 1.4390x over previous
//
#include <hip/hip_runtime.h>
#include <hip/hip_bf16.h>

typedef unsigned int u32;
typedef unsigned short u16;
typedef __attribute__((ext_vector_type(8))) short bf16x8;    // 8 bf16 = 4 VGPRs (MFMA A/B frag)
typedef __attribute__((ext_vector_type(16))) float f32x16;   // MFMA C/D frag
typedef __attribute__((ext_vector_type(4))) u32 u32x4;

// ---------------------------------------------------------------------------
// PillarFeatureNet fused (round 6: R4 kernel VERBATIM, blocks 1024 -> 2048)
//
// Bisection experiment. R4 (1024 blocks): 41.5 us, WRITE exactly 30000 KB.
// R5 (7500 blocks, 5 changes at once): 103 us, WRITE exactly 150000 KB (5x).
// This round changes ONLY the grid: 2048 blocks = 8192 waves = 8 blocks/CU
// resident (VGPR 36 allows 32 waves/CU), ~7.3 pairs/wave, prefetch kept.
// Readout: WRITE_SIZE clean (30000) => grid benign, occupancy win.
//          WRITE_SIZE amplified     => resident-wave/XCD write interaction.
// ---------------------------------------------------------------------------

#define XOFF (0.08f)            // vx/2 + pc_range[0]
#define YOFF (0.08f - 39.68f)   // vy/2 + pc_range[1]

__device__ __forceinline__ u32 f2bf_bits(float f) {
    union { float f; u32 u; } v; v.f = f;
    u32 u = v.u;
    u += 0x7fffu + ((u >> 16) & 1u);   // RNE
    return u >> 16;
}
__device__ __forceinline__ short bf1(float f) { return (short)f2bf_bits(f); }

// packed bf16 convert: v_cvt_pk_bf16_f32 (1 instr)
__device__ __forceinline__ u32 pk2(float lo, float hi) {
    __hip_bfloat162 h = __float22bfloat162_rn(make_float2(lo, hi));
    union { __hip_bfloat162 h; u32 u; } v; v.h = h;
    return v.u;   // low 16 = lo, high 16 = hi
}

__device__ __forceinline__ float vmax16(const f32x16 v) {
    float a = fmaxf(fmaxf(v[0], v[1]), fmaxf(v[2], v[3]));
    float b = fmaxf(fmaxf(v[4], v[5]), fmaxf(v[6], v[7]));
    float c = fmaxf(fmaxf(v[8], v[9]), fmaxf(v[10], v[11]));
    float d = fmaxf(fmaxf(v[12], v[13]), fmaxf(v[14], v[15]));
    return fmaxf(fmaxf(a, b), fmaxf(c, d));
}

__global__ __launch_bounds__(256, 4)
void pfn_mfma(const float* __restrict__ features,
              const int* __restrict__ num_points,
              const int* __restrict__ coors,
              const float* __restrict__ W,
              const float* __restrict__ gamma,
              const float* __restrict__ beta,
              const float* __restrict__ rmean,
              const float* __restrict__ rvar,
              float* __restrict__ out,
              int n_total)
{
    const int lane = threadIdx.x & 63;
    const int wid  = threadIdx.x >> 6;
    const int half = lane >> 5;          // 0 = pillar A, 1 = pillar B
    const int m    = lane & 31;          // point index / channel within tile
    const int waves_total = gridDim.x * 4;
    const int gwave = blockIdx.x * 4 + wid;

    // ---- per-wave setup: fold BN into W, build B-frags -------------------
    const int c0 = m, c1 = 32 + m;       // tile0 ch 0..31, tile1 ch 32..63
    const float inv0   = gamma[c0] / sqrtf(rvar[c0] + 1e-3f);
    const float shift0 = beta[c0] - rmean[c0] * inv0;
    float inv1 = 0.0f, shift1 = 0.0f;
    if (c1 < 63) {
        inv1   = gamma[c1] / sqrtf(rvar[c1] + 1e-3f);
        shift1 = beta[c1] - rmean[c1] * inv1;
    }
    const float shift_me = half ? shift1 : shift0;

    // B[k][n]: n = lane&31 (channel within tile), k = half*8 + j
    bf16x8 b0, b1;
#pragma unroll
    for (int j = 0; j < 8; ++j) {
        const int k = half * 8 + j;
        b0[j] = bf1((k < 9) ? W[c0 * 9 + k] * inv0 : 0.0f);
        b1[j] = bf1((k < 9 && c1 < 63) ? W[c1 * 9 + k] * inv1 : 0.0f);
    }

    const float4* featv = reinterpret_cast<const float4*>(features);
    const int iters = (n_total + 2 * waves_total - 1) / (2 * waves_total);

    // ---- register prefetch of iteration 0 --------------------------------
    float4 q = make_float4(0.f, 0.f, 0.f, 0.f);
    int   npts = 1;
    float cxo = 0.f, cyo = 0.f;
    {
        const int n_h = gwave * 2 + half;
        if (n_h < n_total) {
            npts = num_points[n_h];
            cxo = (float)coors[n_h * 4 + 3] * 0.16f + XOFF;
            cyo = (float)coors[n_h * 4 + 2] * 0.16f + YOFF;
            q = featv[(size_t)n_h * 32 + m];
        }
    }

    for (int it = 0; it < iters; ++it) {
        const int nA = (gwave + it * waves_total) * 2;

        // ---- prefetch next iteration (stays in flight across the body) ----
        float4 qn = make_float4(0.f, 0.f, 0.f, 0.f);
        int   npn = 1;
        float cxn = 0.f, cyn = 0.f;
        if (it + 1 < iters) {
            const int n_h = (gwave + (it + 1) * waves_total) * 2 + half;
            if (n_h < n_total) {
                npn = num_points[n_h];
                cxn = (float)coors[n_h * 4 + 3] * 0.16f + XOFF;
                cyn = (float)coors[n_h * 4 + 2] * 0.16f + YOFF;
                qn = featv[(size_t)n_h * 32 + m];
            }
        }

        // ---- centroid: sum ALL 32 points (incl. padding), / num_points ----
        float sx = q.x, sy = q.y, sz = q.z;
#pragma unroll
        for (int d = 1; d < 32; d <<= 1) {
            sx += __shfl_xor(sx, d, 32);
            sy += __shfl_xor(sy, d, 32);
            sz += __shfl_xor(sz, d, 32);
        }
        const float rnp = 1.0f / (float)npts;
        const float mx = sx * rnp, my = sy * rnp, mz = sz * rnp;

        // ---- 9-dim feature, packed bf16, masked ---------------------------
        u32 p0 = pk2(q.x, q.y);
        u32 p1 = pk2(q.z, q.w);
        u32 p2 = pk2(q.x - mx, q.y - my);
        u32 p3 = pk2(q.z - mz, q.x - cxo);
        u32 p4 = pk2(q.y - cyo, 0.0f);
        if (m >= npts) { p0 = 0; p1 = 0; p2 = 0; p3 = 0; p4 = 0; }

        // ---- cross-half exchange: 5 shuffles replace the LDS transpose ----
        const u32 x0 = __shfl_xor(p0, 32);
        const u32 x1 = __shfl_xor(p1, 32);
        const u32 x2 = __shfl_xor(p2, 32);
        const u32 x3 = __shfl_xor(p3, 32);
        const u32 x4 = __shfl_xor(p4, 32);

        // aA: lanes<32 = pillar A k0..7 (own p0..p3); lanes>=32 = k8..15 (x4,0,0,0)
        u32x4 adw, bdw;
        adw[0] = half ? x4 : p0;  adw[1] = half ? 0u : p1;
        adw[2] = half ? 0u : p2;  adw[3] = half ? 0u : p3;
        // aB: lanes<32 = pillar B k0..7 (x0..x3); lanes>=32 = k8..15 (p4,0,0,0)
        bdw[0] = half ? p4 : x0;  bdw[1] = half ? 0u : x1;
        bdw[2] = half ? 0u : x2;  bdw[3] = half ? 0u : x3;
        const bf16x8 aA = __builtin_bit_cast(bf16x8, adw);
        const bf16x8 aB = __builtin_bit_cast(bf16x8, bdw);

        f32x16 cA0 = {}, cA1 = {}, cB0 = {}, cB1 = {};
        cA0 = __builtin_amdgcn_mfma_f32_32x32x16_bf16(aA, b0, cA0, 0, 0, 0);
        cA1 = __builtin_amdgcn_mfma_f32_32x32x16_bf16(aA, b1, cA1, 0, 0, 0);
        cB0 = __builtin_amdgcn_mfma_f32_32x32x16_bf16(aB, b0, cB0, 0, 0, 0);
        cB1 = __builtin_amdgcn_mfma_f32_32x32x16_bf16(aB, b1, cB1, 0, 0, 0);

        // ---- epilogue: row-max (in-lane 16, then xor-32 half merge) -------
        float tA0 = vmax16(cA0), tA1 = vmax16(cA1);
        float tB0 = vmax16(cB0), tB1 = vmax16(cB1);
        tA0 = fmaxf(tA0, __shfl_xor(tA0, 32));
        tA1 = fmaxf(tA1, __shfl_xor(tA1, 32));
        tB0 = fmaxf(tB0, __shfl_xor(tB0, 32));
        tB1 = fmaxf(tB1, __shfl_xor(tB1, 32));

        float vA = fmaxf((half ? tA1 : tA0) + shift_me, 0.0f);
        float vB = fmaxf((half ? tB1 : tB0) + shift_me, 0.0f);

        // channel 63 = num_points; lane 63 needs BOTH pillars' counts
        const float npf = (float)npts;
        const float npA = __shfl(npf, 0);
        const float npB = __shfl(npf, 32);
        if (lane == 63) { vA = npA; vB = npB; }

        if (nA < n_total)     out[(size_t)nA * 64 + lane] = vA;
        if (nA + 1 < n_total) out[(size_t)(nA + 1) * 64 + lane] = vB;

        // rotate prefetch registers
        q = qn; npts = npn; cxo = cxn; cyo = cyn;
    }
}

extern "C" void kernel_launch(void* const* d_in, const int* in_sizes, int n_in,
                              void* d_out, int out_size, void* d_ws, size_t ws_size,
                              hipStream_t stream) {
    const float* features   = (const float*)d_in[0];
    const int*   num_points = (const int*)d_in[1];
    const int*   coors      = (const int*)d_in[2];
    const float* W          = (const float*)d_in[3];
    const float* gamma      = (const float*)d_in[4];
    const float* beta       = (const float*)d_in[5];
    const float* rmean      = (const float*)d_in[6];
    const float* rvar       = (const float*)d_in[7];
    float* out              = (float*)d_out;

    const int n_total = in_sizes[1];   // N pillars

    // BISECTION: only change vs R4 is blocks 1024 -> 2048.
    // 2048 blocks x 4 waves = 8192 waves -> 8 blocks/CU resident,
    // ~7.3 pair-iterations per wave, prefetch + streaming order unchanged.
    const int blocks = 2048;
    pfn_mfma<<<blocks, 256, 0, stream>>>(features, num_points, coors, W,
                                         gamma, beta, rmean, rvar, out, n_total);
}

// Round 7
// 125.168 us; speedup vs baseline: 1.5624x; 1.0857x over previous
//
#include <hip/hip_runtime.h>
#include <hip/hip_bf16.h>

typedef unsigned int u32;
typedef __attribute__((ext_vector_type(8))) short bf16x8;    // 8 bf16 = 4 VGPRs (MFMA A/B frag)
typedef __attribute__((ext_vector_type(16))) float f32x16;   // MFMA C/D frag
typedef __attribute__((ext_vector_type(4))) u32 u32x4;

// ---------------------------------------------------------------------------
// PillarFeatureNet fused (round 7: instruction-diet on the R4/R6 structure)
//
// R6 post-mortem: VALU-instruction-bound at ~50% issue. Diet applied:
//  - accumulator zero hoisted out of the loop (was 64 v_mov/iter)
//  - vmax16 rewritten as max(max(m,a),b) chains -> v_max3_f32 fusion
//  - BN shift folded into MFMA K-column 9 (A[m][9]=1, B[9][ch]=shift):
//    masked rows now produce exactly `shift` inside the matmul, epilogue
//    shift/select logic deleted. relu(max) after pool unchanged.
//  - rcp instead of full-precision divide for 1/num_points
//  - branchless clamped prefetch (no if-guards on loads), 32-bit indices
// ---------------------------------------------------------------------------

#define XOFF (0.08f)            // vx/2 + pc_range[0]
#define YOFF (0.08f - 39.68f)   // vy/2 + pc_range[1]

__device__ __forceinline__ u32 f2bf_bits(float f) {
    union { float f; u32 u; } v; v.f = f;
    u32 u = v.u;
    u += 0x7fffu + ((u >> 16) & 1u);   // RNE
    return u >> 16;
}
__device__ __forceinline__ short bf1(float f) { return (short)f2bf_bits(f); }

// packed bf16 convert: v_cvt_pk_bf16_f32 (1 instr)
__device__ __forceinline__ u32 pk2(float lo, float hi) {
    __hip_bfloat162 h = __float22bfloat162_rn(make_float2(lo, hi));
    union { __hip_bfloat162 h; u32 u; } v; v.h = h;
    return v.u;   // low 16 = lo, high 16 = hi
}

// 16-way max as max3-fusable linear chain: 8 v_max3/v_max ops
__device__ __forceinline__ float vmax16(const f32x16 v) {
    float m = fmaxf(fmaxf(v[0], v[1]), v[2]);
    m = fmaxf(fmaxf(m, v[3]), v[4]);
    m = fmaxf(fmaxf(m, v[5]), v[6]);
    m = fmaxf(fmaxf(m, v[7]), v[8]);
    m = fmaxf(fmaxf(m, v[9]), v[10]);
    m = fmaxf(fmaxf(m, v[11]), v[12]);
    m = fmaxf(fmaxf(m, v[13]), v[14]);
    return fmaxf(m, v[15]);
}

__global__ __launch_bounds__(256, 4)
void pfn_mfma(const float* __restrict__ features,
              const int* __restrict__ num_points,
              const int* __restrict__ coors,
              const float* __restrict__ W,
              const float* __restrict__ gamma,
              const float* __restrict__ beta,
              const float* __restrict__ rmean,
              const float* __restrict__ rvar,
              float* __restrict__ out,
              int n_total)
{
    const int lane = threadIdx.x & 63;
    const int wid  = threadIdx.x >> 6;
    const int half = lane >> 5;          // 0 = pillar A, 1 = pillar B
    const int m    = lane & 31;          // point index / channel within tile
    const int waves_total = gridDim.x * 4;
    const int gwave = blockIdx.x * 4 + wid;

    // ---- per-wave setup: fold BN scale AND shift into W ------------------
    const int c0 = m, c1 = 32 + m;       // tile0 ch 0..31, tile1 ch 32..63
    const float inv0   = gamma[c0] / sqrtf(rvar[c0] + 1e-3f);
    const float shift0 = beta[c0] - rmean[c0] * inv0;
    float inv1 = 0.0f, shift1 = 0.0f;
    if (c1 < 63) {
        inv1   = gamma[c1] / sqrtf(rvar[c1] + 1e-3f);
        shift1 = beta[c1] - rmean[c1] * inv1;
    }

    // B[k][n]: n = lane&31 (channel within tile), k = half*8 + j.
    // k=0..8: BN-scaled weights; k=9: BN shift (pairs with A's constant-1).
    bf16x8 b0, b1;
#pragma unroll
    for (int j = 0; j < 8; ++j) {
        const int k = half * 8 + j;
        float w0v = 0.0f, w1v = 0.0f;
        if (k < 9)       { w0v = W[c0 * 9 + k] * inv0;
                           w1v = (c1 < 63) ? W[c1 * 9 + k] * inv1 : 0.0f; }
        else if (k == 9) { w0v = shift0; w1v = shift1; }
        b0[j] = bf1(w0v);
        b1[j] = bf1(w1v);
    }

    const f32x16 zacc = {};              // hoisted accumulator zero (16 regs)
    const float4* featv = reinterpret_cast<const float4*>(features);
    const int n_pairs = (n_total + 1) >> 1;
    const int iters = (n_pairs + waves_total - 1) / waves_total;

    // ---- branchless clamped prefetch of iteration 0 ----------------------
    int pair = gwave;
    int nh   = min(min(pair, n_pairs - 1) * 2 + half, n_total - 1);
    int npts = num_points[nh];
    int2 cc  = *reinterpret_cast<const int2*>(coors + nh * 4 + 2);  // [y, x]
    float4 q = featv[nh * 32 + m];

    for (int it = 0; it < iters; ++it) {
        // ---- issue next prefetch immediately (clamped, branchless) -------
        const int pn  = pair + waves_total;
        const int nhn = min(min(pn, n_pairs - 1) * 2 + half, n_total - 1);
        const int npn = num_points[nhn];
        const int2 ccn = *reinterpret_cast<const int2*>(coors + nhn * 4 + 2);
        const float4 qn = featv[nhn * 32 + m];

        // ---- centroid: sum ALL 32 points (incl. padding), / num_points ----
        float sx = q.x, sy = q.y, sz = q.z;
#pragma unroll
        for (int d = 1; d < 32; d <<= 1) {
            sx += __shfl_xor(sx, d, 32);
            sy += __shfl_xor(sy, d, 32);
            sz += __shfl_xor(sz, d, 32);
        }
        const float rnp = __builtin_amdgcn_rcpf((float)npts);
        const float mx = sx * rnp, my = sy * rnp, mz = sz * rnp;
        const float cxo = (float)cc.y * 0.16f + XOFF;
        const float cyo = (float)cc.x * 0.16f + YOFF;

        // ---- 9-dim feature + constant-1 (k9), packed bf16, masked ---------
        u32 p0 = pk2(q.x, q.y);
        u32 p1 = pk2(q.z, q.w);
        u32 p2 = pk2(q.x - mx, q.y - my);
        u32 p3 = pk2(q.z - mz, q.x - cxo);
        if (m >= npts) { p0 = 0; p1 = 0; p2 = 0; p3 = 0; }
        const u32 p4 = pk2((m < npts) ? q.y - cyo : 0.0f, 1.0f);  // k9 = 1 always

        // ---- cross-half exchange: 5 shuffles build both A-frags -----------
        const u32 x0 = __shfl_xor(p0, 32);
        const u32 x1 = __shfl_xor(p1, 32);
        const u32 x2 = __shfl_xor(p2, 32);
        const u32 x3 = __shfl_xor(p3, 32);
        const u32 x4 = __shfl_xor(p4, 32);

        // aA: lanes<32 = pillar A k0..7 (own p0..p3); lanes>=32 = k8..15 (x4,0,0,0)
        u32x4 adw, bdw;
        adw[0] = half ? x4 : p0;  adw[1] = half ? 0u : p1;
        adw[2] = half ? 0u : p2;  adw[3] = half ? 0u : p3;
        // aB: lanes<32 = pillar B k0..7 (x0..x3); lanes>=32 = k8..15 (p4,0,0,0)
        bdw[0] = half ? p4 : x0;  bdw[1] = half ? 0u : x1;
        bdw[2] = half ? 0u : x2;  bdw[3] = half ? 0u : x3;
        const bf16x8 aA = __builtin_bit_cast(bf16x8, adw);
        const bf16x8 aB = __builtin_bit_cast(bf16x8, bdw);

        // ---- MFMA + pooled max, pairwise to limit accumulator live range --
        const f32x16 cA0 = __builtin_amdgcn_mfma_f32_32x32x16_bf16(aA, b0, zacc, 0, 0, 0);
        const f32x16 cA1 = __builtin_amdgcn_mfma_f32_32x32x16_bf16(aA, b1, zacc, 0, 0, 0);
        float tA0 = vmax16(cA0);
        float tA1 = vmax16(cA1);
        const f32x16 cB0 = __builtin_amdgcn_mfma_f32_32x32x16_bf16(aB, b0, zacc, 0, 0, 0);
        const f32x16 cB1 = __builtin_amdgcn_mfma_f32_32x32x16_bf16(aB, b1, zacc, 0, 0, 0);
        float tB0 = vmax16(cB0);
        float tB1 = vmax16(cB1);

        tA0 = fmaxf(tA0, __shfl_xor(tA0, 32));
        tA1 = fmaxf(tA1, __shfl_xor(tA1, 32));
        tB0 = fmaxf(tB0, __shfl_xor(tB0, 32));
        tB1 = fmaxf(tB1, __shfl_xor(tB1, 32));

        float vA = fmaxf(half ? tA1 : tA0, 0.0f);   // relu; shift already inside
        float vB = fmaxf(half ? tB1 : tB0, 0.0f);

        // channel 63 = num_points; lane 63 needs BOTH pillars' counts
        const float npf = (float)npts;
        const float npA = __shfl(npf, 0);
        const float npB = __shfl(npf, 32);
        if (lane == 63) { vA = npA; vB = npB; }

        // ---- guarded stores (uniform per wave; only final iter can fail) --
        if (pair < n_pairs) {
            const int nA = pair * 2;
            out[nA * 64 + lane] = vA;
            if (nA + 1 < n_total) out[(nA + 1) * 64 + lane] = vB;
        }

        // rotate prefetch registers
        pair = pn; q = qn; npts = npn; cc = ccn;
    }
}

extern "C" void kernel_launch(void* const* d_in, const int* in_sizes, int n_in,
                              void* d_out, int out_size, void* d_ws, size_t ws_size,
                              hipStream_t stream) {
    const float* features   = (const float*)d_in[0];
    const int*   num_points = (const int*)d_in[1];
    const int*   coors      = (const int*)d_in[2];
    const float* W          = (const float*)d_in[3];
    const float* gamma      = (const float*)d_in[4];
    const float* beta       = (const float*)d_in[5];
    const float* rmean      = (const float*)d_in[6];
    const float* rvar       = (const float*)d_in[7];
    float* out              = (float*)d_out;

    const int n_total = in_sizes[1];   // N pillars

    // 2048 blocks x 4 waves = 8192 waves (R6-verified traffic-clean);
    // ~7.3 pair-iterations per wave, stripe order preserved.
    const int blocks = 2048;
    pfn_mfma<<<blocks, 256, 0, stream>>>(features, num_points, coors, W,
                                         gamma, beta, rmean, rvar, out, n_total);
}

// Round 8
// 124.984 us; speedup vs baseline: 1.5647x; 1.0015x over previous
//
#include <hip/hip_runtime.h>
#include <hip/hip_bf16.h>

typedef unsigned int u32;
typedef __attribute__((ext_vector_type(8))) short bf16x8;    // 8 bf16 = 4 VGPRs (MFMA A/B frag)
typedef __attribute__((ext_vector_type(16))) float f32x16;   // MFMA C/D frag
typedef __attribute__((ext_vector_type(4))) u32 u32x4;

// ---------------------------------------------------------------------------
// PillarFeatureNet fused (round 8: ds_swizzle butterfly + 2-pair ILP body)
//
// R7 post-mortem: kernel ~34 us, limited by the per-iteration serial DS chain
// (5 dependent shuffle stages + 5 exchanges + 4 merges), not occupancy (R6).
// This round:
//  - width-32 butterfly via __builtin_amdgcn_ds_swizzle immediates (no
//    address VALU, cheapest DS op)
//  - epilogue tile-merge via pre-select: 1 exchange/pillar instead of 2;
//    num_points rides the same xor-32 exchange
//  - loop body processes TWO pillar-pairs (4 pillars) with independent
//    chains -> ILP covers DS/MFMA latency inside one wave
// Math identical to R7 (passing, absmax 0.125).
// ---------------------------------------------------------------------------

#define XOFF (0.08f)            // vx/2 + pc_range[0]
#define YOFF (0.08f - 39.68f)   // vy/2 + pc_range[1]

// xor-butterfly swizzle within 32-lane groups: offset=(xor<<10)|0x1F
#define SWZ_ADD(s, imm)                                                        \
    s += __builtin_bit_cast(float, __builtin_amdgcn_ds_swizzle(                \
             __builtin_bit_cast(int, s), imm))

__device__ __forceinline__ u32 f2bf_bits(float f) {
    union { float f; u32 u; } v; v.f = f;
    u32 u = v.u;
    u += 0x7fffu + ((u >> 16) & 1u);   // RNE
    return u >> 16;
}
__device__ __forceinline__ short bf1(float f) { return (short)f2bf_bits(f); }

// packed bf16 convert: v_cvt_pk_bf16_f32 (1 instr)
__device__ __forceinline__ u32 pk2(float lo, float hi) {
    __hip_bfloat162 h = __float22bfloat162_rn(make_float2(lo, hi));
    union { __hip_bfloat162 h; u32 u; } v; v.h = h;
    return v.u;
}

// 16-way max as max3-fusable linear chain
__device__ __forceinline__ float vmax16(const f32x16 v) {
    float m = fmaxf(fmaxf(v[0], v[1]), v[2]);
    m = fmaxf(fmaxf(m, v[3]), v[4]);
    m = fmaxf(fmaxf(m, v[5]), v[6]);
    m = fmaxf(fmaxf(m, v[7]), v[8]);
    m = fmaxf(fmaxf(m, v[9]), v[10]);
    m = fmaxf(fmaxf(m, v[11]), v[12]);
    m = fmaxf(fmaxf(m, v[13]), v[14]);
    return fmaxf(m, v[15]);
}

// front-end: per-point features -> both A-fragments (9 feats + bias-1 col)
__device__ __forceinline__ void frontend(const float4 q, const int npts,
                                         const int2 cc, const int m,
                                         const int half,
                                         bf16x8& aA, bf16x8& aB)
{
    // centroid: sum ALL 32 points (incl. padding), / num_points
    float sx = q.x, sy = q.y, sz = q.z;
    SWZ_ADD(sx, 0x041F); SWZ_ADD(sy, 0x041F); SWZ_ADD(sz, 0x041F);   // xor 1
    SWZ_ADD(sx, 0x081F); SWZ_ADD(sy, 0x081F); SWZ_ADD(sz, 0x081F);   // xor 2
    SWZ_ADD(sx, 0x101F); SWZ_ADD(sy, 0x101F); SWZ_ADD(sz, 0x101F);   // xor 4
    SWZ_ADD(sx, 0x201F); SWZ_ADD(sy, 0x201F); SWZ_ADD(sz, 0x201F);   // xor 8
    SWZ_ADD(sx, 0x401F); SWZ_ADD(sy, 0x401F); SWZ_ADD(sz, 0x401F);   // xor 16

    const float rnp = __builtin_amdgcn_rcpf((float)npts);
    const float mx = sx * rnp, my = sy * rnp, mz = sz * rnp;
    const float cxo = (float)cc.y * 0.16f + XOFF;
    const float cyo = (float)cc.x * 0.16f + YOFF;

    u32 p0 = pk2(q.x, q.y);
    u32 p1 = pk2(q.z, q.w);
    u32 p2 = pk2(q.x - mx, q.y - my);
    u32 p3 = pk2(q.z - mz, q.x - cxo);
    if (m >= npts) { p0 = 0; p1 = 0; p2 = 0; p3 = 0; }
    const u32 p4 = pk2((m < npts) ? q.y - cyo : 0.0f, 1.0f);   // k9 bias col

    // cross-half exchange (xor 32 crosses the 32-group: bpermute path)
    const u32 x0 = __shfl_xor(p0, 32);
    const u32 x1 = __shfl_xor(p1, 32);
    const u32 x2 = __shfl_xor(p2, 32);
    const u32 x3 = __shfl_xor(p3, 32);
    const u32 x4 = __shfl_xor(p4, 32);

    u32x4 adw, bdw;
    adw[0] = half ? x4 : p0;  adw[1] = half ? 0u : p1;
    adw[2] = half ? 0u : p2;  adw[3] = half ? 0u : p3;
    bdw[0] = half ? p4 : x0;  bdw[1] = half ? 0u : x1;
    bdw[2] = half ? 0u : x2;  bdw[3] = half ? 0u : x3;
    aA = __builtin_bit_cast(bf16x8, adw);
    aB = __builtin_bit_cast(bf16x8, bdw);
}

// back-end: MFMA, pooled max, store one pillar-pair
__device__ __forceinline__ void backend(const bf16x8 aA, const bf16x8 aB,
                                        const bf16x8 b0, const bf16x8 b1,
                                        const f32x16 zacc, const int half,
                                        const int lane, const float npf,
                                        const int pairIdx, const int n_pairs,
                                        const int n_total,
                                        float* __restrict__ out)
{
    const f32x16 cA0 = __builtin_amdgcn_mfma_f32_32x32x16_bf16(aA, b0, zacc, 0, 0, 0);
    const f32x16 cA1 = __builtin_amdgcn_mfma_f32_32x32x16_bf16(aA, b1, zacc, 0, 0, 0);
    const float tA0 = vmax16(cA0);
    const float tA1 = vmax16(cA1);
    const f32x16 cB0 = __builtin_amdgcn_mfma_f32_32x32x16_bf16(aB, b0, zacc, 0, 0, 0);
    const f32x16 cB1 = __builtin_amdgcn_mfma_f32_32x32x16_bf16(aB, b1, zacc, 0, 0, 0);
    const float tB0 = vmax16(cB0);
    const float tB1 = vmax16(cB1);

    // pre-select merge: keep the tile this lane outputs, send the tile the
    // partner outputs; one exchange per pillar instead of two.
    const float keepA = half ? tA1 : tA0, sendA = half ? tA0 : tA1;
    const float keepB = half ? tB1 : tB0, sendB = half ? tB0 : tB1;
    float vA = fmaxf(fmaxf(keepA, __shfl_xor(sendA, 32)), 0.0f);   // relu
    float vB = fmaxf(fmaxf(keepB, __shfl_xor(sendB, 32)), 0.0f);

    // channel 63 = num_points. lane63 (half=1): own npf = pillar B,
    // partner's (lane31) npf = pillar A.
    const float npo = __shfl_xor(npf, 32);
    if (lane == 63) { vA = npo; vB = npf; }

    if (pairIdx < n_pairs) {
        const int nA = pairIdx * 2;
        out[nA * 64 + lane] = vA;
        if (nA + 1 < n_total) out[(nA + 1) * 64 + lane] = vB;
    }
}

__global__ __launch_bounds__(256, 4)
void pfn_mfma(const float* __restrict__ features,
              const int* __restrict__ num_points,
              const int* __restrict__ coors,
              const float* __restrict__ W,
              const float* __restrict__ gamma,
              const float* __restrict__ beta,
              const float* __restrict__ rmean,
              const float* __restrict__ rvar,
              float* __restrict__ out,
              int n_total)
{
    const int lane = threadIdx.x & 63;
    const int wid  = threadIdx.x >> 6;
    const int half = lane >> 5;          // 0 = pillar A, 1 = pillar B
    const int m    = lane & 31;          // point index / channel within tile
    const int waves_total = gridDim.x * 4;
    const int gwave = blockIdx.x * 4 + wid;

    // ---- per-wave setup: fold BN scale AND shift into W ------------------
    const int c0 = m, c1 = 32 + m;       // tile0 ch 0..31, tile1 ch 32..63
    const float inv0   = gamma[c0] / sqrtf(rvar[c0] + 1e-3f);
    const float shift0 = beta[c0] - rmean[c0] * inv0;
    float inv1 = 0.0f, shift1 = 0.0f;
    if (c1 < 63) {
        inv1   = gamma[c1] / sqrtf(rvar[c1] + 1e-3f);
        shift1 = beta[c1] - rmean[c1] * inv1;
    }

    // B[k][n]: n = lane&31, k = half*8 + j; k<9 weights, k==9 BN shift
    bf16x8 b0, b1;
#pragma unroll
    for (int j = 0; j < 8; ++j) {
        const int k = half * 8 + j;
        float w0v = 0.0f, w1v = 0.0f;
        if (k < 9)       { w0v = W[c0 * 9 + k] * inv0;
                           w1v = (c1 < 63) ? W[c1 * 9 + k] * inv1 : 0.0f; }
        else if (k == 9) { w0v = shift0; w1v = shift1; }
        b0[j] = bf1(w0v);
        b1[j] = bf1(w1v);
    }

    const f32x16 zacc = {};              // hoisted accumulator zero
    const float4* featv = reinterpret_cast<const float4*>(features);
    const int n_pairs = (n_total + 1) >> 1;
    const int stride  = waves_total * 2;               // 2 pairs per body
    const int iters   = (n_pairs + stride - 1) / stride;

    // branchless clamped load of one pair's inputs
    auto load_pair = [&](int pr, float4& q, int& np, int2& cc) {
        int nh = min(pr, n_pairs - 1) * 2 + half;
        nh = min(nh, n_total - 1);
        np = num_points[nh];
        cc = *reinterpret_cast<const int2*>(coors + nh * 4 + 2);   // [y, x]
        q  = featv[nh * 32 + m];
    };

    int pa = gwave;                      // pair 1; pair 2 = pa + waves_total
    float4 qa, qb; int na_, nb_; int2 ca, cb;
    load_pair(pa, qa, na_, ca);
    load_pair(pa + waves_total, qb, nb_, cb);

    for (int it = 0; it < iters; ++it) {
        // ---- prefetch next body's two pairs (clamped, branchless) --------
        float4 qan, qbn; int nan_, nbn_; int2 can, cbn;
        load_pair(pa + stride, qan, nan_, can);
        load_pair(pa + stride + waves_total, qbn, nbn_, cbn);

        // ---- two independent front-end chains (scheduler interleaves) ----
        bf16x8 aA1, aB1, aA2, aB2;
        frontend(qa, na_, ca, m, half, aA1, aB1);
        frontend(qb, nb_, cb, m, half, aA2, aB2);

        // ---- back-ends (pairwise MFMA keeps <=32 acc regs live) ----------
        backend(aA1, aB1, b0, b1, zacc, half, lane, (float)na_,
                pa,               n_pairs, n_total, out);
        backend(aA2, aB2, b0, b1, zacc, half, lane, (float)nb_,
                pa + waves_total, n_pairs, n_total, out);

        // rotate
        pa += stride;
        qa = qan; na_ = nan_; ca = can;
        qb = qbn; nb_ = nbn_; cb = cbn;
    }
}

extern "C" void kernel_launch(void* const* d_in, const int* in_sizes, int n_in,
                              void* d_out, int out_size, void* d_ws, size_t ws_size,
                              hipStream_t stream) {
    const float* features   = (const float*)d_in[0];
    const int*   num_points = (const int*)d_in[1];
    const int*   coors      = (const int*)d_in[2];
    const float* W          = (const float*)d_in[3];
    const float* gamma      = (const float*)d_in[4];
    const float* beta       = (const float*)d_in[5];
    const float* rmean      = (const float*)d_in[6];
    const float* rvar       = (const float*)d_in[7];
    float* out              = (float*)d_out;

    const int n_total = in_sizes[1];   // N pillars

    // 2048 blocks x 4 waves = 8192 waves (traffic-clean per R6);
    // body = 2 pairs -> ~3.7 bodies/wave.
    const int blocks = 2048;
    pfn_mfma<<<blocks, 256, 0, stream>>>(features, num_points, coors, W,
                                         gamma, beta, rmean, rvar, out, n_total);
}